// Round 1
// baseline (46118.890 us; speedup 1.0000x reference)
//
#include <hip/hip_runtime.h>

// DARTS recurrent cell, MI355X bf16-MFMA implementation.
// T=256, B=256, NINP=NHID=1024. Output: [T,B,1024] fp32.

typedef short short8 __attribute__((ext_vector_type(8)));
typedef float floatx4 __attribute__((ext_vector_type(4)));

__device__ __forceinline__ unsigned short f2bf(float f) {
  unsigned u = __builtin_bit_cast(unsigned, f);
  u += 0x7fffu + ((u >> 16) & 1u);   // round-to-nearest-even
  return (unsigned short)(u >> 16);
}

enum { ACT_SIG = 0, ACT_RELU = 1, ACT_TANH = 2, ACT_ID = 3 };

__device__ __forceinline__ float actf(int a, float h) {
  if (a == ACT_SIG)  return 1.f / (1.f + __expf(-h));
  if (a == ACT_RELU) return fmaxf(h, 0.f);
  if (a == ACT_TANH) return 1.f - 2.f / (__expf(2.f * h) + 1.f);
  return h;
}

struct Job {
  const float* A;              // [256,1024] fp32 (K-half 1 for stage A)
  const float* A2;             // second K-half (stage A only), else nullptr
  const unsigned short* Wt;    // [2048, K] bf16, transposed weights (k contiguous)
  const float* base;           // residual/pred state [256,1024] fp32
  float* out;                  // [256,1024] fp32
  int act;
  int pad;
};
struct Jobs3 { Job j[3]; };

// Computes out = base + sigmoid(c) * (act(h) - base), where [c|h] = A @ W.
// Block tile: 64 batch rows x 32 state cols (=> 64x64 z-tile: 32 c-cols + 32 h-cols).
__global__ __launch_bounds__(256) void cell_gemm(Jobs3 jobs, int K) {
  const Job jb = jobs.j[blockIdx.z];
  const int j0c = blockIdx.x * 32;   // state col base (0..992)
  const int m0  = blockIdx.y * 64;   // batch row base (0..192)

  __shared__ __align__(16) unsigned short As[64][40];  // [m][k], pad to 40
  __shared__ __align__(16) unsigned short Bs[64][40];  // rows 0..31: c-cols, 32..63: h-cols

  const int tid  = threadIdx.x;
  const int r    = tid >> 2;          // 0..63
  const int kq   = (tid & 3) * 8;     // 0,8,16,24
  const int lane = tid & 63;
  const int wave = tid >> 6;          // 0..3
  const int col  = lane & 15;
  const int quad = lane >> 4;

  floatx4 acc[4];
#pragma unroll
  for (int i = 0; i < 4; ++i) acc[i] = (floatx4){0.f, 0.f, 0.f, 0.f};

  // staging row of Wt (global): rows 0..31 -> c cols, 32..63 -> h cols (n+1024)
  const int n_glob = (r < 32) ? (j0c + r) : (1024 + j0c + (r - 32));
  const unsigned short* wrow = jb.Wt + (size_t)n_glob * K;

  for (int k0 = 0; k0 < K; k0 += 32) {
    const float* Ap; int kk;
    if (jb.A2 != nullptr && k0 >= 1024) { Ap = jb.A2; kk = k0 - 1024; }
    else                                { Ap = jb.A;  kk = k0; }

    // ---- stage A tile: 64 rows x 32 k, fp32 -> bf16 ----
    const float4* ap = reinterpret_cast<const float4*>(Ap + (size_t)(m0 + r) * 1024 + kk + kq);
    float4 f0 = ap[0];
    float4 f1 = ap[1];
    uint4 packed;
    packed.x = (unsigned)f2bf(f0.x) | ((unsigned)f2bf(f0.y) << 16);
    packed.y = (unsigned)f2bf(f0.z) | ((unsigned)f2bf(f0.w) << 16);
    packed.z = (unsigned)f2bf(f1.x) | ((unsigned)f2bf(f1.y) << 16);
    packed.w = (unsigned)f2bf(f1.z) | ((unsigned)f2bf(f1.w) << 16);
    *reinterpret_cast<uint4*>(&As[r][kq]) = packed;

    // ---- stage W tile: 64 n-rows x 32 k, bf16 direct ----
    *reinterpret_cast<uint4*>(&Bs[r][kq]) =
        *reinterpret_cast<const uint4*>(wrow + k0 + kq);

    __syncthreads();

    // A-frag: lane holds A[m=lane&15][k=quad*8+j]; wave covers rows wave*16..+16
    short8 a = *reinterpret_cast<const short8*>(&As[wave * 16 + col][quad * 8]);
#pragma unroll
    for (int nt = 0; nt < 4; ++nt) {
      // B-frag: lane holds B[k=quad*8+j][n=lane&15]; Bs stored [n][k]
      short8 b = *reinterpret_cast<const short8*>(&Bs[nt * 16 + col][quad * 8]);
      acc[nt] = __builtin_amdgcn_mfma_f32_16x16x32_bf16(a, b, acc[nt], 0, 0, 0);
    }
    __syncthreads();
  }

  // Epilogue: C/D layout row=(lane>>4)*4+reg, col=lane&15.
  // acc[0],acc[1] = c cols j0c+0..31 ; acc[2],acc[3] = h cols j0c+0..31.
#pragma unroll
  for (int nt = 0; nt < 2; ++nt) {
#pragma unroll
    for (int rr = 0; rr < 4; ++rr) {
      int m = m0 + wave * 16 + quad * 4 + rr;
      int n = j0c + nt * 16 + col;
      float c = acc[nt][rr];
      float h = acc[nt + 2][rr];
      float p = jb.base[(size_t)m * 1024 + n];
      float g = 1.f / (1.f + __expf(-c));
      float av = actf(jb.act, h);
      jb.out[(size_t)m * 1024 + n] = fmaf(g, av - p, p);
    }
  }
}

// Convert fp32 weights -> bf16 transposed [n][k] layout via LDS tile transpose.
// job 0: W0 [2048,2048]; jobs 1..8: Ws[i] [1024,2048].
__global__ __launch_bounds__(256) void conv_w(const float* __restrict__ W0,
                                              const float* __restrict__ Wsrc,
                                              unsigned short* __restrict__ wt) {
  int job = blockIdx.z;
  int K = (job == 0) ? 2048 : 1024;
  int kt = blockIdx.y;
  if (kt * 32 >= K) return;
  int nt = blockIdx.x;
  const float* W = (job == 0) ? W0 : (Wsrc + (size_t)(job - 1) * 1024 * 2048);
  unsigned short* Wt = (job == 0) ? wt
      : (wt + (size_t)2048 * 2048 + (size_t)(job - 1) * 2048 * 1024);

  __shared__ unsigned short tile[32][33];
  int tx = threadIdx.x & 31;
  int ty = threadIdx.x >> 5;  // 0..7
#pragma unroll
  for (int i = 0; i < 4; ++i) {
    int k = kt * 32 + ty + i * 8;
    tile[ty + i * 8][tx] = f2bf(W[(size_t)k * 2048 + nt * 32 + tx]);
  }
  __syncthreads();
#pragma unroll
  for (int i = 0; i < 4; ++i) {
    int n = nt * 32 + ty + i * 8;
    Wt[(size_t)n * K + kt * 32 + tx] = tile[tx][ty + i * 8];
  }
}

__global__ __launch_bounds__(256) void mean8(
    const float* __restrict__ s1, const float* __restrict__ s2,
    const float* __restrict__ s3, const float* __restrict__ s4,
    const float* __restrict__ s5, const float* __restrict__ s6,
    const float* __restrict__ s7, const float* __restrict__ s8,
    float* __restrict__ out) {
  int i = blockIdx.x * 256 + threadIdx.x;  // float4 index over 256*1024/4
  float4 v1 = reinterpret_cast<const float4*>(s1)[i];
  float4 v2 = reinterpret_cast<const float4*>(s2)[i];
  float4 v3 = reinterpret_cast<const float4*>(s3)[i];
  float4 v4 = reinterpret_cast<const float4*>(s4)[i];
  float4 v5 = reinterpret_cast<const float4*>(s5)[i];
  float4 v6 = reinterpret_cast<const float4*>(s6)[i];
  float4 v7 = reinterpret_cast<const float4*>(s7)[i];
  float4 v8 = reinterpret_cast<const float4*>(s8)[i];
  float4 o;
  o.x = (v1.x + v2.x + v3.x + v4.x + v5.x + v6.x + v7.x + v8.x) * 0.125f;
  o.y = (v1.y + v2.y + v3.y + v4.y + v5.y + v6.y + v7.y + v8.y) * 0.125f;
  o.z = (v1.z + v2.z + v3.z + v4.z + v5.z + v6.z + v7.z + v8.z) * 0.125f;
  o.w = (v1.w + v2.w + v3.w + v4.w + v5.w + v6.w + v7.w + v8.w) * 0.125f;
  reinterpret_cast<float4*>(out)[i] = o;
}

extern "C" void kernel_launch(void* const* d_in, const int* in_sizes, int n_in,
                              void* d_out, int out_size, void* d_ws, size_t ws_size,
                              hipStream_t stream) {
  const float* x_all = (const float*)d_in[0];  // [256,256,1024]
  const float* h0    = (const float*)d_in[1];  // [256,1024]
  const float* W0    = (const float*)d_in[2];  // [2048,2048]
  const float* Ws    = (const float*)d_in[3];  // [8,1024,2048]
  float* out = (float*)d_out;                  // [256,256,1024]

  // ws layout: Wt0 bf16 (8MB) | Wt1..8 bf16 (8*4MB) | s0..s8 fp32 (9MB)
  unsigned short* wt0 = (unsigned short*)d_ws;
  unsigned short* wts[8];
  for (int i = 0; i < 8; ++i)
    wts[i] = wt0 + (size_t)2048 * 2048 + (size_t)i * 2048 * 1024;
  float* sbuf = (float*)((char*)d_ws + (size_t)(2048 * 2048 + 8 * 2048 * 1024) * 2);
  float* s[9];
  for (int i = 0; i < 9; ++i) s[i] = sbuf + (size_t)i * 256 * 1024;

  conv_w<<<dim3(64, 64, 9), 256, 0, stream>>>(W0, Ws, wt0);

  const size_t BH = (size_t)256 * 1024;
  for (int t = 0; t < 256; ++t) {
    const float* x_t = x_all + (size_t)t * BH;
    const float* hp  = (t == 0) ? h0 : (out + (size_t)(t - 1) * BH);
    float* o_t = out + (size_t)t * BH;

    Jobs3 J{};
    // stage A: s0 = h + sig(c0)*(tanh(h0c) - h), [c0|h0c] = [x,h] @ W0
    J.j[0] = { x_t, hp, wt0, hp, s[0], ACT_TANH, 0 };
    cell_gemm<<<dim3(32, 4, 1), 256, 0, stream>>>(J, 2048);

    // stage B: s1 = upd(s0, Ws[0], sigmoid)
    J = Jobs3{};
    J.j[0] = { s[0], nullptr, wts[0], s[0], s[1], ACT_SIG, 0 };
    cell_gemm<<<dim3(32, 4, 1), 256, 0, stream>>>(J, 1024);

    // stage C: s2=upd(s1,Ws[1],relu), s3=upd(s1,Ws[2],relu), s4=upd(s1,Ws[3],id)
    J = Jobs3{};
    J.j[0] = { s[1], nullptr, wts[1], s[1], s[2], ACT_RELU, 0 };
    J.j[1] = { s[1], nullptr, wts[2], s[1], s[3], ACT_RELU, 0 };
    J.j[2] = { s[1], nullptr, wts[3], s[1], s[4], ACT_ID,   0 };
    cell_gemm<<<dim3(32, 4, 3), 256, 0, stream>>>(J, 1024);

    // stage D: s5=upd(s2,Ws[4],tanh), s7=upd(s3,Ws[6],tanh)
    J = Jobs3{};
    J.j[0] = { s[2], nullptr, wts[4], s[2], s[5], ACT_TANH, 0 };
    J.j[1] = { s[3], nullptr, wts[6], s[3], s[7], ACT_TANH, 0 };
    cell_gemm<<<dim3(32, 4, 2), 256, 0, stream>>>(J, 1024);

    // stage E: s6=upd(s5,Ws[5],sigmoid), s8=upd(s5,Ws[7],relu)
    J = Jobs3{};
    J.j[0] = { s[5], nullptr, wts[5], s[5], s[6], ACT_SIG,  0 };
    J.j[1] = { s[5], nullptr, wts[7], s[5], s[8], ACT_RELU, 0 };
    cell_gemm<<<dim3(32, 4, 2), 256, 0, stream>>>(J, 1024);

    // h_new = mean(s1..s8)
    mean8<<<dim3(256), 256, 0, stream>>>(s[1], s[2], s[3], s[4],
                                         s[5], s[6], s[7], s[8], o_t);
  }
}

// Round 2
// 44551.181 us; speedup vs baseline: 1.0352x; 1.0352x over previous
//
#include <hip/hip_runtime.h>

// DARTS recurrent cell, MI355X bf16-MFMA, LDS-free pipelined GEMM phases.
// T=256, B=256, NINP=NHID=1024. Output: [T,B,1024] fp32.

typedef short short8 __attribute__((ext_vector_type(8)));
typedef float floatx4 __attribute__((ext_vector_type(4)));

#define MFMA __builtin_amdgcn_mfma_f32_16x16x32_bf16

enum { ACT_SIG = 0, ACT_RELU = 1, ACT_TANH = 2, ACT_ID = 3 };

__device__ __forceinline__ unsigned short f2bf(float f) {
  unsigned u = __builtin_bit_cast(unsigned, f);
  u += 0x7fffu + ((u >> 16) & 1u);   // round-to-nearest-even
  return (unsigned short)(u >> 16);
}

__device__ __forceinline__ float sigf(float z) { return 1.f / (1.f + __expf(-z)); }

__device__ __forceinline__ float actf(int a, float h) {
  if (a == ACT_SIG)  return sigf(h);
  if (a == ACT_RELU) return fmaxf(h, 0.f);
  if (a == ACT_TANH) return 1.f - 2.f / (__expf(2.f * h) + 1.f);
  return h;
}

// ---------------- phase GEMM (stages A..D) ----------------
// out = base + sigmoid(c)*(act(h) - base), [c|h] = A @ W, A bf16 [256][K],
// Wt bf16 [2048][K] (n-major, k-contiguous). Per-wave tile 32m x 32 state-cols.

struct GJob {
  const unsigned short* A;   // bf16 [256][K]
  const unsigned short* Wt;  // bf16 [2048][K]
  const float* base;         // fp32 [256][1024]
  float* out_f;              // fp32 master
  unsigned short* out_b;     // bf16 operand copy (nullable)
  int act;
  int K;                     // 1024 or 2048 (== A row stride)
};
struct GJobs { GJob j[3]; };

struct Set6 { short8 a0, a1, b0, b1, b2, b3; };

__device__ __forceinline__ void load6(Set6& s,
    const unsigned short* pa0, const unsigned short* pa1,
    const unsigned short* pb0, const unsigned short* pb1,
    const unsigned short* pb2, const unsigned short* pb3, int k) {
  s.a0 = *(const short8*)(pa0 + k);
  s.a1 = *(const short8*)(pa1 + k);
  s.b0 = *(const short8*)(pb0 + k);
  s.b1 = *(const short8*)(pb1 + k);
  s.b2 = *(const short8*)(pb2 + k);
  s.b3 = *(const short8*)(pb3 + k);
}

__device__ __forceinline__ void mm6(const Set6& s, floatx4 ac[2][2], floatx4 ah[2][2]) {
  ac[0][0] = MFMA(s.a0, s.b0, ac[0][0], 0, 0, 0);
  ac[1][0] = MFMA(s.a1, s.b0, ac[1][0], 0, 0, 0);
  ac[0][1] = MFMA(s.a0, s.b1, ac[0][1], 0, 0, 0);
  ac[1][1] = MFMA(s.a1, s.b1, ac[1][1], 0, 0, 0);
  ah[0][0] = MFMA(s.a0, s.b2, ah[0][0], 0, 0, 0);
  ah[1][0] = MFMA(s.a1, s.b2, ah[1][0], 0, 0, 0);
  ah[0][1] = MFMA(s.a0, s.b3, ah[0][1], 0, 0, 0);
  ah[1][1] = MFMA(s.a1, s.b3, ah[1][1], 0, 0, 0);
}

__global__ __launch_bounds__(256) void phase_gemm(GJobs jobs) {
  const GJob jb = jobs.j[blockIdx.z];
  const int K = jb.K;
  const int lane = threadIdx.x & 63;
  const int wave = threadIdx.x >> 6;
  const int col = lane & 15, quad = lane >> 4;
  const int m0  = blockIdx.y * 64 + (wave >> 1) * 32;
  const int sc0 = blockIdx.x * 64 + (wave & 1) * 32;

  const unsigned short* pa0 = jb.A + (size_t)(m0 + col) * K + quad * 8;
  const unsigned short* pa1 = pa0 + (size_t)16 * K;
  const unsigned short* pb0 = jb.Wt + (size_t)(sc0 + col) * K + quad * 8;
  const unsigned short* pb1 = pb0 + (size_t)16 * K;
  const unsigned short* pb2 = jb.Wt + (size_t)(1024 + sc0 + col) * K + quad * 8;
  const unsigned short* pb3 = pb2 + (size_t)16 * K;

  floatx4 ac[2][2], ah[2][2];
#pragma unroll
  for (int i = 0; i < 2; ++i)
#pragma unroll
    for (int j = 0; j < 2; ++j) {
      ac[i][j] = (floatx4){0.f, 0.f, 0.f, 0.f};
      ah[i][j] = (floatx4){0.f, 0.f, 0.f, 0.f};
    }

  Set6 s0, s1;
  load6(s0, pa0, pa1, pb0, pb1, pb2, pb3, 0);
  load6(s1, pa0, pa1, pb0, pb1, pb2, pb3, 32);
  for (int k = 64; k < K; k += 64) {
    mm6(s0, ac, ah);
    load6(s0, pa0, pa1, pb0, pb1, pb2, pb3, k);
    mm6(s1, ac, ah);
    load6(s1, pa0, pa1, pb0, pb1, pb2, pb3, k + 32);
  }
  mm6(s0, ac, ah);
  mm6(s1, ac, ah);

  const int act = jb.act;
#pragma unroll
  for (int mi = 0; mi < 2; ++mi)
#pragma unroll
    for (int ni = 0; ni < 2; ++ni)
#pragma unroll
      for (int rr = 0; rr < 4; ++rr) {
        int m = m0 + mi * 16 + quad * 4 + rr;
        int n = sc0 + ni * 16 + col;
        int idx = m * 1024 + n;
        float c = ac[mi][ni][rr];
        float h = ah[mi][ni][rr];
        float p = jb.base[idx];
        float v = fmaf(sigf(c), actf(act, h) - p, p);
        jb.out_f[idx] = v;
        if (jb.out_b) jb.out_b[idx] = f2bf(v);
      }
}

// ---------------- phase E: s6 & s8 (both from s5) + mean + next-step prep ----
struct Set10 { short8 a0, a1, u0, u1, u2, u3, v0, v1, v2, v3; };

__global__ __launch_bounds__(256) void phase_e(
    const unsigned short* __restrict__ A,    // sb(s5) bf16 [256][1024]
    const unsigned short* __restrict__ W5t,  // bf16 [2048][1024]
    const unsigned short* __restrict__ W7t,
    const float* __restrict__ m1, const float* __restrict__ m2,
    const float* __restrict__ m3, const float* __restrict__ m4,
    const float* __restrict__ m5, const float* __restrict__ m7,
    const float* __restrict__ xnext,         // x[t+1] fp32 [256][1024]
    float* __restrict__ out_t,               // d_out + t*BH
    unsigned short* __restrict__ xhb) {      // bf16 [256][2048]
  const int lane = threadIdx.x & 63;
  const int wave = threadIdx.x >> 6;
  const int col = lane & 15, quad = lane >> 4;
  const int m0  = blockIdx.y * 64 + (wave >> 1) * 32;
  const int sc0 = blockIdx.x * 64 + (wave & 1) * 32;
  const int K = 1024;

  const unsigned short* pa0 = A + (size_t)(m0 + col) * K + quad * 8;
  const unsigned short* pa1 = pa0 + (size_t)16 * K;
  const unsigned short* pu0 = W5t + (size_t)(sc0 + col) * K + quad * 8;
  const unsigned short* pu1 = pu0 + (size_t)16 * K;
  const unsigned short* pu2 = W5t + (size_t)(1024 + sc0 + col) * K + quad * 8;
  const unsigned short* pu3 = pu2 + (size_t)16 * K;
  const unsigned short* pv0 = W7t + (size_t)(sc0 + col) * K + quad * 8;
  const unsigned short* pv1 = pv0 + (size_t)16 * K;
  const unsigned short* pv2 = W7t + (size_t)(1024 + sc0 + col) * K + quad * 8;
  const unsigned short* pv3 = pv2 + (size_t)16 * K;

  // acc[0]=c6 acc[1]=h6 acc[2]=c8 acc[3]=h8
  floatx4 acc[4][2][2];
#pragma unroll
  for (int w = 0; w < 4; ++w)
#pragma unroll
    for (int i = 0; i < 2; ++i)
#pragma unroll
      for (int j = 0; j < 2; ++j) acc[w][i][j] = (floatx4){0.f, 0.f, 0.f, 0.f};

  Set10 s0, s1;
#define LOAD10(s, k)                                     \
  do {                                                   \
    s.a0 = *(const short8*)(pa0 + (k));                  \
    s.a1 = *(const short8*)(pa1 + (k));                  \
    s.u0 = *(const short8*)(pu0 + (k));                  \
    s.u1 = *(const short8*)(pu1 + (k));                  \
    s.u2 = *(const short8*)(pu2 + (k));                  \
    s.u3 = *(const short8*)(pu3 + (k));                  \
    s.v0 = *(const short8*)(pv0 + (k));                  \
    s.v1 = *(const short8*)(pv1 + (k));                  \
    s.v2 = *(const short8*)(pv2 + (k));                  \
    s.v3 = *(const short8*)(pv3 + (k));                  \
  } while (0)
#define MM10(s)                                          \
  do {                                                   \
    acc[0][0][0] = MFMA(s.a0, s.u0, acc[0][0][0], 0,0,0);\
    acc[0][1][0] = MFMA(s.a1, s.u0, acc[0][1][0], 0,0,0);\
    acc[0][0][1] = MFMA(s.a0, s.u1, acc[0][0][1], 0,0,0);\
    acc[0][1][1] = MFMA(s.a1, s.u1, acc[0][1][1], 0,0,0);\
    acc[1][0][0] = MFMA(s.a0, s.u2, acc[1][0][0], 0,0,0);\
    acc[1][1][0] = MFMA(s.a1, s.u2, acc[1][1][0], 0,0,0);\
    acc[1][0][1] = MFMA(s.a0, s.u3, acc[1][0][1], 0,0,0);\
    acc[1][1][1] = MFMA(s.a1, s.u3, acc[1][1][1], 0,0,0);\
    acc[2][0][0] = MFMA(s.a0, s.v0, acc[2][0][0], 0,0,0);\
    acc[2][1][0] = MFMA(s.a1, s.v0, acc[2][1][0], 0,0,0);\
    acc[2][0][1] = MFMA(s.a0, s.v1, acc[2][0][1], 0,0,0);\
    acc[2][1][1] = MFMA(s.a1, s.v1, acc[2][1][1], 0,0,0);\
    acc[3][0][0] = MFMA(s.a0, s.v2, acc[3][0][0], 0,0,0);\
    acc[3][1][0] = MFMA(s.a1, s.v2, acc[3][1][0], 0,0,0);\
    acc[3][0][1] = MFMA(s.a0, s.v3, acc[3][0][1], 0,0,0);\
    acc[3][1][1] = MFMA(s.a1, s.v3, acc[3][1][1], 0,0,0);\
  } while (0)

  LOAD10(s0, 0);
  LOAD10(s1, 32);
  for (int k = 64; k < K; k += 64) {
    MM10(s0);
    LOAD10(s0, k);
    MM10(s1);
    LOAD10(s1, k + 32);
  }
  MM10(s0);
  MM10(s1);

#pragma unroll
  for (int mi = 0; mi < 2; ++mi)
#pragma unroll
    for (int ni = 0; ni < 2; ++ni)
#pragma unroll
      for (int rr = 0; rr < 4; ++rr) {
        int m = m0 + mi * 16 + quad * 4 + rr;
        int n = sc0 + ni * 16 + col;
        int idx = m * 1024 + n;
        float b = m5[idx];
        float s6 = fmaf(sigf(acc[0][mi][ni][rr]), sigf(acc[1][mi][ni][rr]) - b, b);
        float s8 = fmaf(sigf(acc[2][mi][ni][rr]), fmaxf(acc[3][mi][ni][rr], 0.f) - b, b);
        float sum = m1[idx] + m2[idx] + m3[idx] + m4[idx] + b + m7[idx] + s6 + s8;
        float hh = sum * 0.125f;
        out_t[idx] = hh;
        xhb[m * 2048 + 1024 + n] = f2bf(hh);
        xhb[m * 2048 + n] = f2bf(xnext[idx]);
      }
}

// ---------------- weight conversion fp32 -> bf16 transposed [n][k] ----------
__global__ __launch_bounds__(256) void conv_w(const float* __restrict__ W0,
                                              const float* __restrict__ Wsrc,
                                              unsigned short* __restrict__ wt) {
  int job = blockIdx.z;
  int K = (job == 0) ? 2048 : 1024;
  int kt = blockIdx.y;
  if (kt * 32 >= K) return;
  int nt = blockIdx.x;
  const float* W = (job == 0) ? W0 : (Wsrc + (size_t)(job - 1) * 1024 * 2048);
  unsigned short* Wt = (job == 0) ? wt
      : (wt + (size_t)2048 * 2048 + (size_t)(job - 1) * 2048 * 1024);

  __shared__ unsigned short tile[32][33];
  int tx = threadIdx.x & 31;
  int ty = threadIdx.x >> 5;  // 0..7
#pragma unroll
  for (int i = 0; i < 4; ++i) {
    int k = kt * 32 + ty + i * 8;
    tile[ty + i * 8][tx] = f2bf(W[(size_t)k * 2048 + nt * 32 + tx]);
  }
  __syncthreads();
#pragma unroll
  for (int i = 0; i < 4; ++i) {
    int n = nt * 32 + ty + i * 8;
    Wt[(size_t)n * K + kt * 32 + tx] = tile[tx][ty + i * 8];
  }
}

// ---------------- init: xhb = [bf16(x0) | bf16(h0)] ----------
__global__ __launch_bounds__(256) void init_xh(const float* __restrict__ x0,
                                               const float* __restrict__ h0,
                                               unsigned short* __restrict__ xhb) {
  int i = blockIdx.x * 256 + threadIdx.x;  // 0..262143
  int m = i >> 10, n = i & 1023;
  xhb[m * 2048 + n] = f2bf(x0[i]);
  xhb[m * 2048 + 1024 + n] = f2bf(h0[i]);
}

extern "C" void kernel_launch(void* const* d_in, const int* in_sizes, int n_in,
                              void* d_out, int out_size, void* d_ws, size_t ws_size,
                              hipStream_t stream) {
  const float* x_all = (const float*)d_in[0];  // [256,256,1024]
  const float* h0    = (const float*)d_in[1];  // [256,1024]
  const float* W0    = (const float*)d_in[2];  // [2048,2048]
  const float* Ws    = (const float*)d_in[3];  // [8,1024,2048]
  float* out = (float*)d_out;                  // [256,256,1024]

  const size_t BH = (size_t)256 * 1024;

  // ws layout: Wt (41.94 MB) | masters fp32 s0..s5,s7 (7 MB) | sb bf16
  // s0,s1,s2,s3,s5 (2.62 MB) | xhb bf16 (1.05 MB)
  unsigned short* wt0 = (unsigned short*)d_ws;
  unsigned short* wts[8];
  for (int i = 0; i < 8; ++i)
    wts[i] = wt0 + (size_t)2048 * 2048 + (size_t)i * 2048 * 1024;
  float* smbase = (float*)((char*)d_ws +
      (size_t)(2048 * 2048 + 8 * 2048 * 1024) * 2);
  // master slots: 0:s0 1:s1 2:s2 3:s3 4:s4 5:s5 6:s7
  float* sm[7];
  for (int i = 0; i < 7; ++i) sm[i] = smbase + (size_t)i * BH;
  unsigned short* sbbase = (unsigned short*)(smbase + (size_t)7 * BH);
  // bf16 operand slots: 0:s0 1:s1 2:s2 3:s3 4:s5
  unsigned short* sb[5];
  for (int i = 0; i < 5; ++i) sb[i] = sbbase + (size_t)i * BH;
  unsigned short* xhb = sbbase + (size_t)5 * BH;  // [256][2048]

  conv_w<<<dim3(64, 64, 9), 256, 0, stream>>>(W0, Ws, wt0);
  init_xh<<<dim3(1024), 256, 0, stream>>>(x_all, h0, xhb);

  for (int t = 0; t < 256; ++t) {
    const float* hp = (t == 0) ? h0 : (out + (size_t)(t - 1) * BH);
    float* o_t = out + (size_t)t * BH;
    const float* xnext = x_all + (size_t)((t < 255) ? t + 1 : 255) * BH;

    GJobs J{};
    // A: s0 = h + sig(c)*(tanh(h') - h), [c|h'] = [x,h] @ W0, K=2048
    J.j[0] = { xhb, wt0, hp, sm[0], sb[0], ACT_TANH, 2048 };
    phase_gemm<<<dim3(16, 4, 1), 256, 0, stream>>>(J);

    // B: s1 = upd(s0, Ws[0], sigmoid)
    J = GJobs{};
    J.j[0] = { sb[0], wts[0], sm[0], sm[1], sb[1], ACT_SIG, 1024 };
    phase_gemm<<<dim3(16, 4, 1), 256, 0, stream>>>(J);

    // C: s2 = upd(s1, Ws[1], relu), s3 = upd(s1, Ws[2], relu)
    J = GJobs{};
    J.j[0] = { sb[1], wts[1], sm[1], sm[2], sb[2], ACT_RELU, 1024 };
    J.j[1] = { sb[1], wts[2], sm[1], sm[3], sb[3], ACT_RELU, 1024 };
    phase_gemm<<<dim3(16, 4, 2), 256, 0, stream>>>(J);

    // D: s5 = upd(s2, Ws[4], tanh), s7 = upd(s3, Ws[6], tanh), s4 = upd(s1, Ws[3], id)
    J = GJobs{};
    J.j[0] = { sb[2], wts[4], sm[2], sm[5], sb[4], ACT_TANH, 1024 };
    J.j[1] = { sb[3], wts[6], sm[3], sm[6], nullptr, ACT_TANH, 1024 };
    J.j[2] = { sb[1], wts[3], sm[1], sm[4], nullptr, ACT_ID, 1024 };
    phase_gemm<<<dim3(16, 4, 3), 256, 0, stream>>>(J);

    // E: s6 = upd(s5, Ws[5], sigmoid), s8 = upd(s5, Ws[7], relu), h = mean(s1..s8)
    phase_e<<<dim3(16, 4, 1), 256, 0, stream>>>(
        sb[4], wts[5], wts[7],
        sm[1], sm[2], sm[3], sm[4], sm[5], sm[6],
        xnext, o_t, xhb);
  }
}